// Round 3
// baseline (779.363 us; speedup 1.0000x reference)
//
#include <hip/hip_runtime.h>

typedef float v4f __attribute__((ext_vector_type(4)));
typedef short v8s __attribute__((ext_vector_type(8)));

// round-to-nearest-even fp32 -> bf16 (scalar, prep kernels)
__device__ __forceinline__ unsigned short f2bf_rn(float f) {
  unsigned u = __float_as_uint(f);
  return (unsigned short)((u + 0x7fffu + ((u >> 16) & 1u)) >> 16);
}
__device__ __forceinline__ float bf2f(unsigned short h) {
  return __uint_as_float((unsigned)h << 16);
}
// packed RNE fp32x2 -> bf16x2 (single HW op; no builtin on gfx950)
__device__ __forceinline__ unsigned cvt_pk_bf16(float lo, float hi) {
  unsigned r;
  asm("v_cvt_pk_bf16_f32 %0, %1, %2" : "=v"(r) : "v"(lo), "v"(hi));
  return r;
}

// tanh-approx gelu (JAX default) scaled by 1/PHI_C
__device__ __forceinline__ float gelu_phi(float x) {
  float t = tanhf(0.7978845608f * (x + 0.044715f * x * x * x));
  return 0.5f * x * (1.0f + t) * 1.5338375f;
}

// ---------------- MLP + input prep ----------------
__global__ __launch_bounds__(256) void k_mlp1(const float* __restrict__ emb, const float* __restrict__ W0,
                                              const float* __restrict__ x1, const float* __restrict__ x2,
                                              float* __restrict__ act1,
                                              unsigned short* __restrict__ s1c, unsigned short* __restrict__ v1c,
                                              unsigned short* __restrict__ s2c, unsigned short* __restrict__ v2c)
{
  const int blk = blockIdx.x, tid = threadIdx.x;
  if (blk < 128) {
    float s = 0.f;
#pragma unroll 8
    for (int xx = 0; xx < 64; ++xx) s += emb[blk * 64 + xx] * W0[xx * 256 + tid];
    act1[blk * 256 + tid] = gelu_phi(s * 0.125f);
  } else {
    const int sel = (blk - 128) >> 3;
    const float* xs = sel ? x2 : x1;
    unsigned short* sc = sel ? s2c : s1c;
    unsigned short* vc = sel ? v2c : v1c;
    for (int i = ((blk - 128) & 7) * 256 + tid; i < 32768; i += 2048) {
      if (i < 8192) {
        sc[i] = f2bf_rn(xs[(i >> 6) * 256 + (i & 63)]);
      } else {
        const int t = i - 8192, g = t >> 13, r = t & 8191;
        vc[g * 8192 + r] = f2bf_rn(xs[(r >> 6) * 256 + 64 + (r & 63) * 3 + g]);
      }
    }
  }
}

__global__ __launch_bounds__(256) void k_mlp2(const float* __restrict__ act1, const float* __restrict__ W1,
                                              float* __restrict__ act2)
{
  const int b = blockIdx.x, j = threadIdx.x;
  float s = 0.f;
#pragma unroll 16
  for (int x = 0; x < 256; ++x) s += act1[b * 256 + x] * W1[x * 256 + j];
  act2[b * 256 + j] = gelu_phi(s * 0.0625f);
}

__global__ __launch_bounds__(256) void k_mlp3(const float* __restrict__ act2, const float* __restrict__ W2,
                                              float* __restrict__ hsT)
{
  const int o = blockIdx.x * 256 + threadIdx.x;
  const int b = o >> 6, e = o & 63;
  float s = 0.f;
#pragma unroll 16
  for (int x = 0; x < 256; ++x) s += act2[b * 256 + x] * W2[x * 64 + e];
  hsT[e * 128 + b] = gelu_phi(s * 0.0625f) * 0.125f;  // hs transposed [x][b]
}

// ---------------- fused tensor-product GEMM ----------------
// out-rows (M=1408) x K=(x,u,v)=262144 x N=w=64, A built in registers:
//   G0 (P0): rows b           : A = hs[x]*s1[u]*s2[v]
//   G1 (P1): rows 128+j*128+b : A = hs[x]*s1[u]*v2_j[v]
//   G2 (P2): rows 512+i*128+b : A = hs[x]*v1_i[u]*s2[v]
//   G3 (P3): rows 896+b       : A = hs[x]*sum_i v1_i[u]*v2_i[v]
//   G4 (P4): rows 1024+k*128+b: A = hs[x]*(v1_{k+1}[u]*v2_{k+2}[v] - v1_{k+2}[u]*v2_{k+1}[v])
// Pipeline: NSET rotating register prefetch sets. ALL register-array indices are
// compile-time literals (rule #20): phases repeat mod 4, loop steps by 4, the step
// body is a macro parameterized by literal phase PH.

template<int G>
__device__ __forceinline__ void gemm_body(
    const float* __restrict__ P,
    const unsigned short* __restrict__ f1g,   // s1c or v1c  [comp][128][64] bf16
    const unsigned short* __restrict__ f2g,   // s2c or v2c
    const float* __restrict__ hsT,            // [64][128] f32
    float* __restrict__ partial,
    int c, int csh,
    unsigned short* ldsF1, unsigned* ldsB32)
{
  constexpr int NC   = (G == 0 || G == 3) ? 1 : 3;  // output comps per bh
  constexpr int NF2  = (G == 0 || G == 2) ? 1 : 3;  // f2 rows kept in regs
  constexpr int NH   = (G == 0 || G == 1) ? 1 : 3;  // f1 comps (h scalars)
  constexpr int NCM  = (G <= 1) ? 1 : 3;            // f1 comps staged in LDS
  constexpr int RB   = (G == 0) ? 0 : (G == 1) ? 128 : (G == 2) ? 512 : (G == 3) ? 896 : 1024;
  constexpr int NSET = (G == 1 || G == 4) ? 2 : 4;  // prefetch depth (reg-pressure bound)

  const int tid = threadIdx.x;
  const int lane = tid & 63, w = tid >> 6, l16 = lane & 15, quad = lane >> 4;
  const int tq = tid & 15, kp = tid >> 4;
  const int x = c >> (csh - 6);
  const int nsub = 1 << (7 - csh);

  int bidx[2];
  bidx[0] = w * 32 + l16;
  bidx[1] = w * 32 + 16 + l16;

  float hsx[2];
  hsx[0] = hsT[x * 128 + bidx[0]];
  hsx[1] = hsT[x * 128 + bidx[1]];

  // f2 fragments: [bh][comp][v-half], 8 bf16 each at v = h*32 + quad*8 + j
  v8s fr2[2][NF2][2];
#pragma unroll
  for (int bh = 0; bh < 2; ++bh)
#pragma unroll
    for (int m = 0; m < NF2; ++m)
#pragma unroll
      for (int hh = 0; hh < 2; ++hh)
        fr2[bh][m][hh] = *(const v8s*)(f2g + m * 8192 + bidx[bh] * 64 + hh * 32 + quad * 8);

  v4f acc[2][NC][4];
#pragma unroll
  for (int bh = 0; bh < 2; ++bh)
#pragma unroll
    for (int cc = 0; cc < NC; ++cc)
#pragma unroll
      for (int nf = 0; nf < 4; ++nf) acc[bh][cc][nf] = (v4f){0.f, 0.f, 0.f, 0.f};

  // LDS col-dword swizzle: physical col = col ^ ((((row>>2)&3) ^ ((row>>4)&3)) << 2)
  const int swz_w = (((tq & 3) ^ (tq >> 2)) << 2);  // write rows 4tq..4tq+3 share this

  float h[2][NH];
  float4 A0[NSET], A1[NSET];

  // A-fragment scalar: vh is a LITERAL at every call site -> fr2 indices static
  auto PV = [&](int bh, int cc, int vh, int j) -> float {
    if constexpr (G == 0)
      return h[bh][0] * bf2f((unsigned short)fr2[bh][0][vh][j]);
    else if constexpr (G == 1)
      return h[bh][0] * bf2f((unsigned short)fr2[bh][cc][vh][j]);
    else if constexpr (G == 2)
      return h[bh][cc] * bf2f((unsigned short)fr2[bh][0][vh][j]);
    else if constexpr (G == 3)
      return h[bh][0] * bf2f((unsigned short)fr2[bh][0][vh][j])
           + h[bh][1] * bf2f((unsigned short)fr2[bh][1][vh][j])
           + h[bh][2] * bf2f((unsigned short)fr2[bh][2][vh][j]);
    else {
      const int i1 = (cc + 1) % 3, j2 = (cc + 2) % 3;
      return h[bh][i1] * bf2f((unsigned short)fr2[bh][j2][vh][j])
           - h[bh][j2] * bf2f((unsigned short)fr2[bh][i1][vh][j]);
    }
  };

// global load of k-step KK into set S (S literal)
#define TP_GLOAD(KK, S)                                                         \
  {                                                                             \
    const float* p_ = P + (size_t)(kb + (KK) * 32 + 2 * kp) * 64 + 4 * tq;      \
    A0[(S)] = *(const float4*)p_;                                               \
    A1[(S)] = *(const float4*)(p_ + 64);                                        \
  }

// convert+stage set S into LDS buffer BUF (both literal)
#define TP_BWRITE(BUF, S)                                                       \
  {                                                                             \
    unsigned* d_ = ldsB32 + ((BUF) * 64 + 4 * tq) * 20 + (kp ^ swz_w);          \
    d_[0]  = cvt_pk_bf16(A0[(S)].x, A1[(S)].x);                                 \
    d_[20] = cvt_pk_bf16(A0[(S)].y, A1[(S)].y);                                 \
    d_[40] = cvt_pk_bf16(A0[(S)].z, A1[(S)].z);                                 \
    d_[60] = cvt_pk_bf16(A0[(S)].w, A1[(S)].w);                                 \
  }

// one 32-k step. KK runtime (addresses only); PH/WR/LD literals (indices/branches)
#define TP_STEP(KK, PH, WR, LD)                                                 \
  {                                                                             \
    constexpr int buf_ = (PH) & 1;                                              \
    constexpr int vh_ = (PH) & 1;                                               \
    constexpr int sN_ = ((PH) + 1) & (NSET - 1);                                \
    v8s bfr[4];                                                                 \
    _Pragma("unroll") for (int nf = 0; nf < 4; ++nf)                            \
        bfr[nf] = *(const v8s*)&ldsB32[(buf_ * 64 + nf * 16 + l16) * 20 +       \
                                       ((quad * 4) ^ ((((l16 >> 2) & 3) ^ nf) << 2))]; \
    if constexpr (vh_ == 0) {                                                   \
      const int uu_ = (KK) >> 1;                                                \
      _Pragma("unroll") for (int bh = 0; bh < 2; ++bh)                          \
          _Pragma("unroll") for (int m = 0; m < NH; ++m)                        \
              h[bh][m] = hsx[bh] * bf2f(ldsF1[m * 5120 + bidx[bh] * 40 + uu_]); \
    }                                                                           \
    if constexpr (WR) TP_BWRITE(buf_ ^ 1, sN_);                                 \
    if constexpr (LD) TP_GLOAD((KK) + 1 + NSET, sN_);                           \
    _Pragma("unroll") for (int bh = 0; bh < 2; ++bh) {                          \
      _Pragma("unroll") for (int cc = 0; cc < NC; ++cc) {                       \
        v8s af;                                                                 \
        unsigned* a32_ = (unsigned*)&af;                                        \
        _Pragma("unroll") for (int t = 0; t < 4; ++t)                           \
            a32_[t] = cvt_pk_bf16(PV(bh, cc, vh_, 2 * t), PV(bh, cc, vh_, 2 * t + 1)); \
        _Pragma("unroll") for (int nf = 0; nf < 4; ++nf)                        \
            acc[bh][cc][nf] =                                                   \
                __builtin_amdgcn_mfma_f32_16x16x32_bf16(af, bfr[nf], acc[bh][cc][nf], 0, 0, 0); \
      }                                                                         \
    }                                                                           \
    __syncthreads();                                                            \
  }

  for (int sub = 0; sub < nsub; ++sub) {
    const int kb = (c << (18 - csh)) + (sub << 11);  // k-base, 2048 k's per sub
    const int u0 = (kb >> 6) & 63;
    __syncthreads();  // prior sub's LDS reads done
    // stage f1 slice [NCM][128][u0..u0+32) into ldsF1 [cm][b][40-padded]
    {
      const int nchk = NCM * 512;
      for (int i = tid; i < nchk; i += 256) {
        const int uu8 = i & 3, b = (i >> 2) & 127, cm = i >> 9;
        *(v8s*)&ldsF1[(cm * 128 + b) * 40 + uu8 * 8] =
            *(const v8s*)(f1g + cm * 8192 + b * 64 + u0 + uu8 * 8);
      }
    }

    // prologue: fill all sets, stage step 0 into buf 0, refill set 0 far ahead
    TP_GLOAD(0, 0)
    TP_GLOAD(1, 1)
    if constexpr (NSET == 4) {
      TP_GLOAD(2, 2)
      TP_GLOAD(3, 3)
    }
    TP_BWRITE(0, 0)
    TP_GLOAD(NSET, 0)
    __syncthreads();  // f1 slice + buf0 visible

    // main loop: steps 0..55; phase = literal i (k4 multiple of 4 by construction)
    for (int k4 = 0; k4 < 56; k4 += 4) {
      TP_STEP(k4 + 0, 0, true, true)
      TP_STEP(k4 + 1, 1, true, true)
      TP_STEP(k4 + 2, 2, true, true)
      TP_STEP(k4 + 3, 3, true, true)
    }
    // tail: steps 56..63 — wr while steps remain, ld while targets < 64
    TP_STEP(56, 0, true, (0 < 7 - NSET))
    TP_STEP(57, 1, true, (1 < 7 - NSET))
    TP_STEP(58, 2, true, (2 < 7 - NSET))
    TP_STEP(59, 3, true, (3 < 7 - NSET))
    TP_STEP(60, 0, true, (4 < 7 - NSET))
    TP_STEP(61, 1, true, (5 < 7 - NSET))
    TP_STEP(62, 2, true, false)
    TP_STEP(63, 3, false, false)
  }

#undef TP_STEP
#undef TP_BWRITE
#undef TP_GLOAD

  // epilogue: C/D layout col=l16, row=quad*4+r ; disjoint per-chunk partials
#pragma unroll
  for (int bh = 0; bh < 2; ++bh)
#pragma unroll
    for (int cc = 0; cc < NC; ++cc)
#pragma unroll
      for (int nf = 0; nf < 4; ++nf)
#pragma unroll
        for (int r = 0; r < 4; ++r) {
          const int row = RB + cc * 128 + w * 32 + bh * 16 + quad * 4 + r;
          partial[((size_t)c * 1408 + row) * 64 + nf * 16 + l16] = acc[bh][cc][nf][r];
        }
}

__global__ __launch_bounds__(256, 2) void tp_gemm(
    const float* __restrict__ P0, const float* __restrict__ P1, const float* __restrict__ P2,
    const float* __restrict__ P3, const float* __restrict__ P4,
    const unsigned short* __restrict__ s1c, const unsigned short* __restrict__ v1c,
    const unsigned short* __restrict__ s2c, const unsigned short* __restrict__ v2c,
    const float* __restrict__ hsT, float* __restrict__ partial, int csh)
{
  __shared__ __align__(16) unsigned ldsB32[2 * 64 * 20];        // double-buffered B tile, swizzled
  __shared__ __align__(16) unsigned short ldsF1[3 * 128 * 40];  // f1 slice [comp][b][u], padded
  const int g = blockIdx.x >> csh;
  const int c = blockIdx.x & ((1 << csh) - 1);
  switch (g) {
    case 0: gemm_body<0>(P0, s1c, s2c, hsT, partial, c, csh, ldsF1, ldsB32); break;
    case 1: gemm_body<1>(P1, s1c, v2c, hsT, partial, c, csh, ldsF1, ldsB32); break;
    case 2: gemm_body<2>(P2, v1c, s2c, hsT, partial, c, csh, ldsF1, ldsB32); break;
    case 3: gemm_body<3>(P3, v1c, v2c, hsT, partial, c, csh, ldsF1, ldsB32); break;
    default: gemm_body<4>(P4, v1c, v2c, hsT, partial, c, csh, ldsF1, ldsB32); break;
  }
}

// ---------------- finalize: sum K-chunk partials, assemble output ----------------
__global__ __launch_bounds__(448) void k_fin(const float* __restrict__ partial, float* __restrict__ out, int nch)
{
  const int b = blockIdx.x, i = threadIdx.x;
  int w, rA, rB;
  if (i < 64)       { w = i; rA = b; rB = 896 + b; }
  else if (i < 256) { const int t = i - 64;  w = t / 3; const int j = t - 3 * w; rA = 128 + j * 128 + b; rB = 512 + j * 128 + b; }
  else              { const int t = i - 256; w = t / 3; const int k = t - 3 * w; rA = 1024 + k * 128 + b; rB = rA; }
  const float* pA = partial + (size_t)rA * 64 + w;
  const float* pB = partial + (size_t)rB * 64 + w;
  float sA = 0.f, sB = 0.f;
#pragma unroll 8
  for (int cc = 0; cc < nch; ++cc) {
    sA += pA[(size_t)cc * 90112];
    sB += pB[(size_t)cc * 90112];
  }
  const float A01 = 0.011048543f;            // 1/sqrt(2*64*64)
  const float sc = 0.015625f * 0.70710678f;  // ALPHA_2 * INV_SQ2
  float o;
  if (i < 64)       o = A01 * (sA + 0.57735027f * sB);  // t0 + INV_SQ3*t3
  else if (i < 256) o = A01 * (sA + sB);                // t1 + t2
  else              o = sc * sA;                        // eps-combined t4
  out[b * 448 + i] = o;
}

extern "C" void kernel_launch(void* const* d_in, const int* in_sizes, int n_in,
                              void* d_out, int out_size, void* d_ws, size_t ws_size,
                              hipStream_t stream)
{
  const float* emb = (const float*)d_in[0];
  const float* x1  = (const float*)d_in[1];
  const float* x2  = (const float*)d_in[2];
  const float* W0  = (const float*)d_in[3];
  const float* W1  = (const float*)d_in[4];
  const float* W2  = (const float*)d_in[5];
  const float* P0  = (const float*)d_in[6];
  const float* P1  = (const float*)d_in[7];
  const float* P2  = (const float*)d_in[8];
  const float* P3  = (const float*)d_in[9];
  const float* P4  = (const float*)d_in[10];
  float* out = (float*)d_out;
  char* ws = (char*)d_ws;

  // persistent region (live during tp_gemm): [0, 163840)
  float* hsT = (float*)ws;                                // 32768 B
  unsigned short* s1c = (unsigned short*)(ws + 32768);    // 16384 B
  unsigned short* v1c = (unsigned short*)(ws + 49152);    // 49152 B
  unsigned short* s2c = (unsigned short*)(ws + 98304);    // 16384 B
  unsigned short* v2c = (unsigned short*)(ws + 114688);   // 49152 B
  // MLP activations alias the partial buffer (dead before tp_gemm runs)
  float* act1 = (float*)(ws + 163840);                    // 131072 B
  float* act2 = (float*)(ws + 294912);                    // 131072 B
  float* partial = (float*)(ws + 163840);                 // nch * 1408 * 64 * 4 B

  const int csh = (ws_size >= (size_t)163840 + ((size_t)360448 << 7)) ? 7 : 6;

  k_mlp1<<<144, 256, 0, stream>>>(emb, W0, x1, x2, act1, s1c, v1c, s2c, v2c);
  k_mlp2<<<128, 256, 0, stream>>>(act1, W1, act2);
  k_mlp3<<<32, 256, 0, stream>>>(act2, W2, hsT);
  tp_gemm<<<5 << csh, 256, 0, stream>>>(P0, P1, P2, P3, P4, s1c, v1c, s2c, v2c, hsT, partial, csh);
  k_fin<<<128, 448, 0, stream>>>(partial, out, 1 << csh);
}

// Round 4
// 497.028 us; speedup vs baseline: 1.5680x; 1.5680x over previous
//
#include <hip/hip_runtime.h>

typedef float v4f __attribute__((ext_vector_type(4)));
typedef short v8s __attribute__((ext_vector_type(8)));

// round-to-nearest-even fp32 -> bf16 (scalar, prep kernels)
__device__ __forceinline__ unsigned short f2bf_rn(float f) {
  unsigned u = __float_as_uint(f);
  return (unsigned short)((u + 0x7fffu + ((u >> 16) & 1u)) >> 16);
}
__device__ __forceinline__ float bf2f(unsigned short h) {
  return __uint_as_float((unsigned)h << 16);
}
// packed RNE fp32x2 -> bf16x2 (single HW op; no builtin on gfx950)
__device__ __forceinline__ unsigned cvt_pk_bf16(float lo, float hi) {
  unsigned r;
  asm("v_cvt_pk_bf16_f32 %0, %1, %2" : "=v"(r) : "v"(lo), "v"(hi));
  return r;
}

// raw barrier WITHOUT vmcnt drain: ds ops flushed (cross-wave visibility),
// global prefetch loads stay in flight across the barrier (T4).
__device__ __forceinline__ void barrier_keep_vmcnt() {
  asm volatile("s_waitcnt lgkmcnt(0)" ::: "memory");
  __builtin_amdgcn_s_barrier();
}

// tanh-approx gelu (JAX default) scaled by 1/PHI_C
__device__ __forceinline__ float gelu_phi(float x) {
  float t = tanhf(0.7978845608f * (x + 0.044715f * x * x * x));
  return 0.5f * x * (1.0f + t) * 1.5338375f;
}

// ---------------- fused 3-layer MLP (row-wise) + input prep ----------------
// blocks 0..127: MLP row b (all 3 layers, LDS-staged activations)
// blocks 128..143: bf16 compaction of x1/x2 s/v parts
__global__ __launch_bounds__(256) void k_mlp(const float* __restrict__ emb, const float* __restrict__ W0,
                                             const float* __restrict__ W1, const float* __restrict__ W2,
                                             const float* __restrict__ x1, const float* __restrict__ x2,
                                             float* __restrict__ hsT,
                                             unsigned short* __restrict__ s1c, unsigned short* __restrict__ v1c,
                                             unsigned short* __restrict__ s2c, unsigned short* __restrict__ v2c)
{
  const int blk = blockIdx.x, tid = threadIdx.x;
  if (blk < 128) {
    __shared__ float er[64];
    __shared__ float a1[256];
    __shared__ float a2[256];
    __shared__ float r3[4][64];
    const int b = blk;
    if (tid < 64) er[tid] = emb[b * 64 + tid];
    __syncthreads();
    // layer 1: 256 outs, K=64
    {
      float s = 0.f;
#pragma unroll 8
      for (int x = 0; x < 64; ++x) s += er[x] * W0[x * 256 + tid];
      a1[tid] = gelu_phi(s * 0.125f);
    }
    __syncthreads();
    // layer 2: 256 outs, K=256
    {
      float s = 0.f;
#pragma unroll 16
      for (int x = 0; x < 256; ++x) s += a1[x] * W1[x * 256 + tid];
      a2[tid] = gelu_phi(s * 0.0625f);
    }
    __syncthreads();
    // layer 3: 64 outs, K=256 split 4 ways
    {
      const int e = tid & 63, q = tid >> 6;
      float s = 0.f;
#pragma unroll 16
      for (int x = q * 64; x < q * 64 + 64; ++x) s += a2[x] * W2[x * 64 + e];
      r3[q][e] = s;
    }
    __syncthreads();
    if (tid < 64) {
      const float s = r3[0][tid] + r3[1][tid] + r3[2][tid] + r3[3][tid];
      hsT[tid * 128 + b] = gelu_phi(s * 0.0625f) * 0.125f;  // hs transposed [x][b]
    }
  } else {
    const int sel = (blk - 128) >> 3;
    const float* xs = sel ? x2 : x1;
    unsigned short* sc = sel ? s2c : s1c;
    unsigned short* vc = sel ? v2c : v1c;
    for (int i = ((blk - 128) & 7) * 256 + tid; i < 32768; i += 2048) {
      if (i < 8192) {
        sc[i] = f2bf_rn(xs[(i >> 6) * 256 + (i & 63)]);
      } else {
        const int t = i - 8192, g = t >> 13, r = t & 8191;
        vc[g * 8192 + r] = f2bf_rn(xs[(r >> 6) * 256 + 64 + (r & 63) * 3 + g]);
      }
    }
  }
}

// ---------------- fused tensor-product GEMM ----------------
// out-rows (M=1408) x K=(x,u,v)=262144 x N=w=64, A built in registers:
//   G0 (P0): rows b           : A = hs[x]*s1[u]*s2[v]
//   G1 (P1): rows 128+j*128+b : A = hs[x]*s1[u]*v2_j[v]
//   G2 (P2): rows 512+i*128+b : A = hs[x]*v1_i[u]*s2[v]
//   G3 (P3): rows 896+b       : A = hs[x]*sum_i v1_i[u]*v2_i[v]
//   G4 (P4): rows 1024+k*128+b: A = hs[x]*(v1_{k+1}[u]*v2_{k+2}[v] - v1_{k+2}[u]*v2_{k+1}[v])
// Round-1 structure (single prefetch reg set, no spills) + barrier_keep_vmcnt so
// the prefetch survives the per-step barrier (no vmcnt(0) drain).

template<int G>
__device__ __forceinline__ void gemm_body(
    const float* __restrict__ P,
    const unsigned short* __restrict__ f1g,   // s1c or v1c  [comp][128][64] bf16
    const unsigned short* __restrict__ f2g,   // s2c or v2c
    const float* __restrict__ hsT,            // [64][128] f32
    float* __restrict__ partial,
    int c, int csh,
    unsigned short* ldsF1, unsigned* ldsB32)
{
  constexpr int NC  = (G == 0 || G == 3) ? 1 : 3;  // output comps per bh
  constexpr int NF2 = (G == 0 || G == 2) ? 1 : 3;  // f2 rows kept in regs
  constexpr int NH  = (G == 0 || G == 1) ? 1 : 3;  // f1 comps (h scalars)
  constexpr int NCM = (G <= 1) ? 1 : 3;            // f1 comps staged in LDS
  constexpr int RB  = (G == 0) ? 0 : (G == 1) ? 128 : (G == 2) ? 512 : (G == 3) ? 896 : 1024;

  const int tid = threadIdx.x;
  const int lane = tid & 63, w = tid >> 6, l16 = lane & 15, quad = lane >> 4;
  const int tq = tid & 15, kp = tid >> 4;
  const int x = c >> (csh - 6);
  const int nsub = 1 << (7 - csh);

  int bidx[2];
  bidx[0] = w * 32 + l16;
  bidx[1] = w * 32 + 16 + l16;

  float hsx[2];
  hsx[0] = hsT[x * 128 + bidx[0]];
  hsx[1] = hsT[x * 128 + bidx[1]];

  // f2 fragments: [bh][comp][v-half], 8 bf16 each at v = h*32 + quad*8 + j
  v8s fr2[2][NF2][2];
#pragma unroll
  for (int bh = 0; bh < 2; ++bh)
#pragma unroll
    for (int m = 0; m < NF2; ++m)
#pragma unroll
      for (int hh = 0; hh < 2; ++hh)
        fr2[bh][m][hh] = *(const v8s*)(f2g + m * 8192 + bidx[bh] * 64 + hh * 32 + quad * 8);

  v4f acc[2][NC][4];
#pragma unroll
  for (int bh = 0; bh < 2; ++bh)
#pragma unroll
    for (int cc = 0; cc < NC; ++cc)
#pragma unroll
      for (int nf = 0; nf < 4; ++nf) acc[bh][cc][nf] = (v4f){0.f, 0.f, 0.f, 0.f};

  // LDS col-dword swizzle: physical col = col ^ ((((row>>2)&3) ^ ((row>>4)&3)) << 2)
  const int swz_w = (((tq & 3) ^ (tq >> 2)) << 2);  // write rows 4tq..4tq+3 share this

  float h[2][NH];

  for (int sub = 0; sub < nsub; ++sub) {
    const int kb = (c << (18 - csh)) + (sub << 11);  // k-base, 2048 k's per sub
    const int u0 = (kb >> 6) & 63;
    __syncthreads();  // once per sub: prior sub's LDS reads done (full drain OK here)
    // stage f1 slice [NCM][128][u0..u0+32) into ldsF1 [cm][b][40-padded]
    {
      const int nchk = NCM * 512;
      for (int i = tid; i < nchk; i += 256) {
        const int uu8 = i & 3, b = (i >> 2) & 127, cm = i >> 9;
        *(v8s*)&ldsF1[(cm * 128 + b) * 40 + uu8 * 8] =
            *(const v8s*)(f1g + cm * 8192 + b * 64 + u0 + uu8 * 8);
      }
    }

    // B staging helpers: thread loads rows (2kp,2kp+1), cols 4tq..4tq+3 (coalesced)
    float4 pa0, pa1;  // single prefetch set (round-1 structure: no arrays -> no spills)
    auto gload = [&](int kk) {
      const float* s = P + (size_t)(kb + kk * 32 + 2 * kp) * 64 + 4 * tq;
      pa0 = *(const float4*)s;
      pa1 = *(const float4*)(s + 64);
    };
    auto bwrite = [&](int buf) {
      unsigned* dst = ldsB32 + (buf * 64 + 4 * tq) * 20 + (kp ^ swz_w);
      dst[0]  = cvt_pk_bf16(pa0.x, pa1.x);
      dst[20] = cvt_pk_bf16(pa0.y, pa1.y);
      dst[40] = cvt_pk_bf16(pa0.z, pa1.z);
      dst[60] = cvt_pk_bf16(pa0.w, pa1.w);
    };

    // prologue: fill buf0, prefetch step 1 (stays in flight across raw barrier)
    gload(0);
    bwrite(0);
    gload(1);
    barrier_keep_vmcnt();  // f1 slice + buf0 visible; gload(1) NOT drained

#pragma unroll 2
    for (int kk = 0; kk < 64; ++kk) {
      const int buf = kk & 1;
      const int vh = kk & 1;  // v-half of this step
      // B fragments for this step (read current buffer first)
      v8s bfr[4];
#pragma unroll
      for (int nf = 0; nf < 4; ++nf)
        bfr[nf] = *(const v8s*)&ldsB32[(buf * 64 + nf * 16 + l16) * 20 +
                                       ((quad * 4) ^ ((((l16 >> 2) & 3) ^ nf) << 2))];
      // u changes every 2 steps: refresh h scalars from LDS f1 slice
      if (vh == 0) {
        const int uu = kk >> 1;
#pragma unroll
        for (int bh = 0; bh < 2; ++bh)
#pragma unroll
          for (int m = 0; m < NH; ++m)
            h[bh][m] = hsx[bh] * bf2f(ldsF1[m * 5120 + bidx[bh] * 40 + uu]);
      }
      // pipeline: write next buffer (waits its load, counted), prefetch kk+2
      if (kk < 63) bwrite(buf ^ 1);
      if (kk < 62) gload(kk + 2);
      // A fragments + MFMA
#pragma unroll
      for (int bh = 0; bh < 2; ++bh) {
#pragma unroll
        for (int cc = 0; cc < NC; ++cc) {
          auto pv = [&](int j) -> float {
            if constexpr (G == 0)
              return h[bh][0] * bf2f((unsigned short)(vh ? fr2[bh][0][1][j] : fr2[bh][0][0][j]));
            else if constexpr (G == 1)
              return h[bh][0] * bf2f((unsigned short)(vh ? fr2[bh][cc][1][j] : fr2[bh][cc][0][j]));
            else if constexpr (G == 2)
              return h[bh][cc] * bf2f((unsigned short)(vh ? fr2[bh][0][1][j] : fr2[bh][0][0][j]));
            else if constexpr (G == 3)
              return h[bh][0] * bf2f((unsigned short)(vh ? fr2[bh][0][1][j] : fr2[bh][0][0][j]))
                   + h[bh][1] * bf2f((unsigned short)(vh ? fr2[bh][1][1][j] : fr2[bh][1][0][j]))
                   + h[bh][2] * bf2f((unsigned short)(vh ? fr2[bh][2][1][j] : fr2[bh][2][0][j]));
            else {
              const int i1 = (cc + 1) % 3, j2 = (cc + 2) % 3;
              return h[bh][i1] * bf2f((unsigned short)(vh ? fr2[bh][j2][1][j] : fr2[bh][j2][0][j]))
                   - h[bh][j2] * bf2f((unsigned short)(vh ? fr2[bh][i1][1][j] : fr2[bh][i1][0][j]));
            }
          };
          v8s af;
          unsigned* a32 = (unsigned*)&af;
#pragma unroll
          for (int t = 0; t < 4; ++t)
            a32[t] = cvt_pk_bf16(pv(2 * t), pv(2 * t + 1));
#pragma unroll
          for (int nf = 0; nf < 4; ++nf)
            acc[bh][cc][nf] = __builtin_amdgcn_mfma_f32_16x16x32_bf16(af, bfr[nf], acc[bh][cc][nf], 0, 0, 0);
        }
      }
      barrier_keep_vmcnt();  // ds flushed; prefetch loads stay in flight
    }
  }

  // epilogue: C/D layout col=l16, row=quad*4+r ; disjoint per-chunk partials
#pragma unroll
  for (int bh = 0; bh < 2; ++bh)
#pragma unroll
    for (int cc = 0; cc < NC; ++cc)
#pragma unroll
      for (int nf = 0; nf < 4; ++nf)
#pragma unroll
        for (int r = 0; r < 4; ++r) {
          const int row = RB + cc * 128 + w * 32 + bh * 16 + quad * 4 + r;
          partial[((size_t)c * 1408 + row) * 64 + nf * 16 + l16] = acc[bh][cc][nf][r];
        }
}

__global__ __launch_bounds__(256, 2) void tp_gemm(
    const float* __restrict__ P0, const float* __restrict__ P1, const float* __restrict__ P2,
    const float* __restrict__ P3, const float* __restrict__ P4,
    const unsigned short* __restrict__ s1c, const unsigned short* __restrict__ v1c,
    const unsigned short* __restrict__ s2c, const unsigned short* __restrict__ v2c,
    const float* __restrict__ hsT, float* __restrict__ partial, int csh)
{
  __shared__ __align__(16) unsigned ldsB32[2 * 64 * 20];        // double-buffered B tile, swizzled
  __shared__ __align__(16) unsigned short ldsF1[3 * 128 * 40];  // f1 slice [comp][b][u], padded
  const int g = blockIdx.x >> csh;
  const int c = blockIdx.x & ((1 << csh) - 1);
  switch (g) {
    case 0: gemm_body<0>(P0, s1c, s2c, hsT, partial, c, csh, ldsF1, ldsB32); break;
    case 1: gemm_body<1>(P1, s1c, v2c, hsT, partial, c, csh, ldsF1, ldsB32); break;
    case 2: gemm_body<2>(P2, v1c, s2c, hsT, partial, c, csh, ldsF1, ldsB32); break;
    case 3: gemm_body<3>(P3, v1c, v2c, hsT, partial, c, csh, ldsF1, ldsB32); break;
    default: gemm_body<4>(P4, v1c, v2c, hsT, partial, c, csh, ldsF1, ldsB32); break;
  }
}

// ---------------- finalize: sum K-chunk partials, assemble output ----------------
__global__ __launch_bounds__(448) void k_fin(const float* __restrict__ partial, float* __restrict__ out, int nch)
{
  const int b = blockIdx.x, i = threadIdx.x;
  int w, rA, rB;
  if (i < 64)       { w = i; rA = b; rB = 896 + b; }
  else if (i < 256) { const int t = i - 64;  w = t / 3; const int j = t - 3 * w; rA = 128 + j * 128 + b; rB = 512 + j * 128 + b; }
  else              { const int t = i - 256; w = t / 3; const int k = t - 3 * w; rA = 1024 + k * 128 + b; rB = rA; }
  const float* pA = partial + (size_t)rA * 64 + w;
  const float* pB = partial + (size_t)rB * 64 + w;
  float sA = 0.f, sB = 0.f;
#pragma unroll 8
  for (int cc = 0; cc < nch; ++cc) {
    sA += pA[(size_t)cc * 90112];
    sB += pB[(size_t)cc * 90112];
  }
  const float A01 = 0.011048543f;            // 1/sqrt(2*64*64)
  const float sc = 0.015625f * 0.70710678f;  // ALPHA_2 * INV_SQ2
  float o;
  if (i < 64)       o = A01 * (sA + 0.57735027f * sB);  // t0 + INV_SQ3*t3
  else if (i < 256) o = A01 * (sA + sB);                // t1 + t2
  else              o = sc * sA;                        // eps-combined t4
  out[b * 448 + i] = o;
}

extern "C" void kernel_launch(void* const* d_in, const int* in_sizes, int n_in,
                              void* d_out, int out_size, void* d_ws, size_t ws_size,
                              hipStream_t stream)
{
  const float* emb = (const float*)d_in[0];
  const float* x1  = (const float*)d_in[1];
  const float* x2  = (const float*)d_in[2];
  const float* W0  = (const float*)d_in[3];
  const float* W1  = (const float*)d_in[4];
  const float* W2  = (const float*)d_in[5];
  const float* P0  = (const float*)d_in[6];
  const float* P1  = (const float*)d_in[7];
  const float* P2  = (const float*)d_in[8];
  const float* P3  = (const float*)d_in[9];
  const float* P4  = (const float*)d_in[10];
  float* out = (float*)d_out;
  char* ws = (char*)d_ws;

  // persistent region (live during tp_gemm): [0, 163840)
  float* hsT = (float*)ws;                                // 32768 B
  unsigned short* s1c = (unsigned short*)(ws + 32768);    // 16384 B
  unsigned short* v1c = (unsigned short*)(ws + 49152);    // 49152 B
  unsigned short* s2c = (unsigned short*)(ws + 98304);    // 16384 B
  unsigned short* v2c = (unsigned short*)(ws + 114688);   // 49152 B
  float* partial = (float*)(ws + 163840);                 // nch * 1408 * 64 * 4 B

  const int csh = (ws_size >= (size_t)163840 + ((size_t)360448 << 7)) ? 7 : 6;

  k_mlp<<<144, 256, 0, stream>>>(emb, W0, W1, W2, x1, x2, hsT, s1c, v1c, s2c, v2c);
  tp_gemm<<<5 << csh, 256, 0, stream>>>(P0, P1, P2, P3, P4, s1c, v1c, s2c, v2c, hsT, partial, csh);
  k_fin<<<128, 448, 0, stream>>>(partial, out, 1 << csh);
}

// Round 5
// 420.423 us; speedup vs baseline: 1.8538x; 1.1822x over previous
//
#include <hip/hip_runtime.h>

typedef float v4f __attribute__((ext_vector_type(4)));
typedef short v8s __attribute__((ext_vector_type(8)));

// round-to-nearest-even fp32 -> bf16
__device__ __forceinline__ unsigned short f2bf_rn(float f) {
  unsigned u = __float_as_uint(f);
  return (unsigned short)((u + 0x7fffu + ((u >> 16) & 1u)) >> 16);
}
__device__ __forceinline__ float bf2f(unsigned short h) {
  return __uint_as_float((unsigned)h << 16);
}

// tanh-approx gelu (JAX default) scaled by 1/PHI_C
__device__ __forceinline__ float gelu_phi(float x) {
  float t = tanhf(0.7978845608f * (x + 0.044715f * x * x * x));
  return 0.5f * x * (1.0f + t) * 1.5338375f;
}

// ---------------- fused 3-layer MLP (row-wise) + input prep ----------------
__global__ __launch_bounds__(256) void k_mlp(const float* __restrict__ emb, const float* __restrict__ W0,
                                             const float* __restrict__ W1, const float* __restrict__ W2,
                                             const float* __restrict__ x1, const float* __restrict__ x2,
                                             float* __restrict__ hsT,
                                             unsigned short* __restrict__ s1c, unsigned short* __restrict__ v1c,
                                             unsigned short* __restrict__ s2c, unsigned short* __restrict__ v2c)
{
  const int blk = blockIdx.x, tid = threadIdx.x;
  if (blk < 128) {
    __shared__ float er[64];
    __shared__ float a1[256];
    __shared__ float a2[256];
    __shared__ float r3[4][64];
    const int b = blk;
    if (tid < 64) er[tid] = emb[b * 64 + tid];
    __syncthreads();
    {
      float s = 0.f;
#pragma unroll 8
      for (int x = 0; x < 64; ++x) s += er[x] * W0[x * 256 + tid];
      a1[tid] = gelu_phi(s * 0.125f);
    }
    __syncthreads();
    {
      float s = 0.f;
#pragma unroll 16
      for (int x = 0; x < 256; ++x) s += a1[x] * W1[x * 256 + tid];
      a2[tid] = gelu_phi(s * 0.0625f);
    }
    __syncthreads();
    {
      const int e = tid & 63, q = tid >> 6;
      float s = 0.f;
#pragma unroll 16
      for (int x = q * 64; x < q * 64 + 64; ++x) s += a2[x] * W2[x * 64 + e];
      r3[q][e] = s;
    }
    __syncthreads();
    if (tid < 64) {
      const float s = r3[0][tid] + r3[1][tid] + r3[2][tid] + r3[3][tid];
      hsT[tid * 128 + b] = gelu_phi(s * 0.0625f) * 0.125f;  // hs transposed [x][b]
    }
  } else {
    const int sel = (blk - 128) >> 3;
    const float* xs = sel ? x2 : x1;
    unsigned short* sc = sel ? s2c : s1c;
    unsigned short* vc = sel ? v2c : v1c;
    for (int i = ((blk - 128) & 7) * 256 + tid; i < 32768; i += 2048) {
      if (i < 8192) {
        sc[i] = f2bf_rn(xs[(i >> 6) * 256 + (i & 63)]);
      } else {
        const int t = i - 8192, g = t >> 13, r = t & 8191;
        vc[g * 8192 + r] = f2bf_rn(xs[(r >> 6) * 256 + 64 + (r & 63) * 3 + g]);
      }
    }
  }
}

// ---------------- fused tensor-product GEMM ----------------
// out-rows (M=1408) x K=(x,u,v)=262144 x N=w=64, A built in registers:
//   G0 (P0): rows b           : A = hs[x]*s1[u]*s2[v]            (full n, 64 cols)
//   G1 (P1): rows 128+j*128+b : A = hs[x]*s1[u]*v2_j[v]          (n-split, 32 cols/block)
//   G2 (P2): rows 512+i*128+b : A = hs[x]*v1_i[u]*s2[v]          (n-split)
//   G3 (P3): rows 896+b       : A = hs[x]*sum_i v1_i[u]*v2_i[v]  (full n)
//   G4 (P4): rows 1024+k*128+b: A = hs[x]*(v1_{k+1}[u]*v2_{k+2}[v] - v1_{k+2}[u]*v2_{k+1}[v]) (n-split)
// Inner loop is the verified round-1 structure: single prefetch reg pair, double-
// buffered LDS bf16 B tile, __syncthreads per 32-k step. n-split halves the tile
// width for the expensive groups to equalize block cost and double block count.

template<int G, int HALF>
__device__ __forceinline__ void gemm_body(
    const float* __restrict__ P,
    const unsigned short* __restrict__ f1g,   // s1c or v1c  [comp][128][64] bf16
    const unsigned short* __restrict__ f2g,   // s2c or v2c
    const float* __restrict__ hsT,            // [64][128] f32
    float* __restrict__ partial,
    int c, int csh, int nh,
    unsigned short* ldsF1, unsigned* ldsB32)
{
  constexpr int NC  = (G == 0 || G == 3) ? 1 : 3;  // output comps per bh
  constexpr int NF2 = (G == 0 || G == 2) ? 1 : 3;  // f2 rows kept in regs
  constexpr int NH  = (G == 0 || G == 1) ? 1 : 3;  // f1 comps (h scalars)
  constexpr int NCM = (G <= 1) ? 1 : 3;            // f1 comps staged in LDS
  constexpr int RB  = (G == 0) ? 0 : (G == 1) ? 128 : (G == 2) ? 512 : (G == 3) ? 896 : 1024;
  constexpr int NF  = HALF ? 2 : 4;                // 16-wide n-tiles per block

  const int tid = threadIdx.x;
  const int lane = tid & 63, w = tid >> 6, l16 = lane & 15, quad = lane >> 4;
  const int x = c >> (csh - 6);
  const int nsub = 1 << (7 - csh);
  const int n0 = nh * 32;

  // staging thread mapping: FULL: 256 thr cover 32k x 64n; HALF: 128 thr cover 32k x 32n
  const int tq = HALF ? (tid & 7) : (tid & 15);
  const int kp = HALF ? ((tid >> 3) & 15) : (tid >> 4);
  const bool stg = HALF ? (tid < 128) : true;

  int bidx[2];
  bidx[0] = w * 32 + l16;
  bidx[1] = w * 32 + 16 + l16;

  float hsx[2];
  hsx[0] = hsT[x * 128 + bidx[0]];
  hsx[1] = hsT[x * 128 + bidx[1]];

  // f2 fragments: [bh][comp][v-half], 8 bf16 each at v = h*32 + quad*8 + j
  v8s fr2[2][NF2][2];
#pragma unroll
  for (int bh = 0; bh < 2; ++bh)
#pragma unroll
    for (int m = 0; m < NF2; ++m)
#pragma unroll
      for (int hh = 0; hh < 2; ++hh)
        fr2[bh][m][hh] = *(const v8s*)(f2g + m * 8192 + bidx[bh] * 64 + hh * 32 + quad * 8);

  v4f acc[2][NC][NF];
#pragma unroll
  for (int bh = 0; bh < 2; ++bh)
#pragma unroll
    for (int cc = 0; cc < NC; ++cc)
#pragma unroll
      for (int nf = 0; nf < NF; ++nf) acc[bh][cc][nf] = (v4f){0.f, 0.f, 0.f, 0.f};

  // round-1 swizzle: write rows 4tq..4tq+3 at dword col kp ^ ((tq&3)<<2);
  // read row n: col (quad*4) ^ (((n>>2)&3)<<2) = (quad*4) ^ (((l16>>2)&3)<<2)
  const int swz_w = (tq & 3) << 2;
  const int swz_r = ((l16 >> 2) & 3) << 2;

  float h[2][NH];

  for (int sub = 0; sub < nsub; ++sub) {
    const int kb = (c << (18 - csh)) + (sub << 11);  // k-base, 2048 k's per sub
    const int u0 = (kb >> 6) & 63;
    __syncthreads();  // prior sub's LDS reads done
    // stage f1 slice [NCM][128][u0..u0+32) into ldsF1 [cm][b][40-padded]
    {
      const int nchk = NCM * 512;
      for (int i = tid; i < nchk; i += 256) {
        const int uu8 = i & 3, b = (i >> 2) & 127, cm = i >> 9;
        *(v8s*)&ldsF1[(cm * 128 + b) * 40 + uu8 * 8] =
            *(const v8s*)(f1g + cm * 8192 + b * 64 + u0 + uu8 * 8);
      }
    }

    float4 pa0, pa1;  // single prefetch set (round-1: no arrays -> no spills)
    auto gload = [&](int kk) {
      const float* s = P + (size_t)(kb + kk * 32 + 2 * kp) * 64 + n0 + 4 * tq;
      pa0 = *(const float4*)s;
      pa1 = *(const float4*)(s + 64);
    };
    auto bwrite = [&](int buf) {
      unsigned* dst = ldsB32 + (buf * (NF * 16) + 4 * tq) * 20 + (kp ^ swz_w);
      dst[0]  = (unsigned)f2bf_rn(pa0.x) | ((unsigned)f2bf_rn(pa1.x) << 16);
      dst[20] = (unsigned)f2bf_rn(pa0.y) | ((unsigned)f2bf_rn(pa1.y) << 16);
      dst[40] = (unsigned)f2bf_rn(pa0.z) | ((unsigned)f2bf_rn(pa1.z) << 16);
      dst[60] = (unsigned)f2bf_rn(pa0.w) | ((unsigned)f2bf_rn(pa1.w) << 16);
    };

    // prologue: fill buf0, prefetch step 1
    if (stg) {
      gload(0);
      bwrite(0);
      gload(1);
    }
    __syncthreads();  // f1 slice + buf0 visible

#pragma unroll 2
    for (int kk = 0; kk < 64; ++kk) {
      const int buf = kk & 1;
      const int vh = kk & 1;  // v-half of this step (kb/32 even by construction)
      // B fragments for this step (read current buffer first)
      v8s bfr[NF];
#pragma unroll
      for (int nf = 0; nf < NF; ++nf)
        bfr[nf] = *(const v8s*)&ldsB32[(buf * (NF * 16) + nf * 16 + l16) * 20 +
                                       ((quad * 4) ^ swz_r)];
      // u changes every 2 steps: refresh h scalars from LDS f1 slice
      if (vh == 0) {
        const int uu = kk >> 1;
#pragma unroll
        for (int bh = 0; bh < 2; ++bh)
#pragma unroll
          for (int m = 0; m < NH; ++m)
            h[bh][m] = hsx[bh] * bf2f(ldsF1[m * 5120 + bidx[bh] * 40 + uu]);
      }
      // pipeline: write next buffer (waits its load), prefetch kk+2
      if (stg) {
        if (kk < 63) bwrite(buf ^ 1);
        if (kk < 62) gload(kk + 2);
      }
      // A fragments + MFMA (round-1 truncating pack)
#pragma unroll
      for (int bh = 0; bh < 2; ++bh) {
#pragma unroll
        for (int cc = 0; cc < NC; ++cc) {
          v8s af;
#pragma unroll
          for (int j = 0; j < 8; ++j) {
            float p;
            if constexpr (G == 0)
              p = h[bh][0] * bf2f((unsigned short)fr2[bh][0][vh][j]);
            else if constexpr (G == 1)
              p = h[bh][0] * bf2f((unsigned short)fr2[bh][cc][vh][j]);
            else if constexpr (G == 2)
              p = h[bh][cc] * bf2f((unsigned short)fr2[bh][0][vh][j]);
            else if constexpr (G == 3)
              p = h[bh][0] * bf2f((unsigned short)fr2[bh][0][vh][j])
                + h[bh][1] * bf2f((unsigned short)fr2[bh][1][vh][j])
                + h[bh][2] * bf2f((unsigned short)fr2[bh][2][vh][j]);
            else {
              const int i1 = (cc + 1) % 3, j2 = (cc + 2) % 3;
              p = h[bh][i1] * bf2f((unsigned short)fr2[bh][j2][vh][j])
                - h[bh][j2] * bf2f((unsigned short)fr2[bh][i1][vh][j]);
            }
            af[j] = (short)(__float_as_uint(p) >> 16);  // truncating bf16 (unbiased noise)
          }
#pragma unroll
          for (int nf = 0; nf < NF; ++nf)
            acc[bh][cc][nf] = __builtin_amdgcn_mfma_f32_16x16x32_bf16(af, bfr[nf], acc[bh][cc][nf], 0, 0, 0);
        }
      }
      __syncthreads();
    }
  }

  // epilogue: C/D layout col=l16, row=quad*4+r ; disjoint per-chunk/half partials
#pragma unroll
  for (int bh = 0; bh < 2; ++bh)
#pragma unroll
    for (int cc = 0; cc < NC; ++cc)
#pragma unroll
      for (int nf = 0; nf < NF; ++nf)
#pragma unroll
        for (int r = 0; r < 4; ++r) {
          const int row = RB + cc * 128 + w * 32 + bh * 16 + quad * 4 + r;
          const int col = n0 + nf * 16 + l16;
          partial[((size_t)c * 1408 + row) * 64 + col] = acc[bh][cc][nf][r];
        }
}

// block slots per chunk (cost-interleaved): [G0, G1h0, G1h1, G2h0, G2h1, G3, G4h0, G4h1]
__global__ __launch_bounds__(256, 2) void tp_gemm(
    const float* __restrict__ P0, const float* __restrict__ P1, const float* __restrict__ P2,
    const float* __restrict__ P3, const float* __restrict__ P4,
    const unsigned short* __restrict__ s1c, const unsigned short* __restrict__ v1c,
    const unsigned short* __restrict__ s2c, const unsigned short* __restrict__ v2c,
    const float* __restrict__ hsT, float* __restrict__ partial, int csh)
{
  __shared__ __align__(16) unsigned ldsB32[2 * 64 * 20];        // double-buffered B tile, swizzled
  __shared__ __align__(16) unsigned short ldsF1[3 * 128 * 40];  // f1 slice [comp][b][u], padded
  const int slot = blockIdx.x & 7;
  const int c = blockIdx.x >> 3;
  switch (slot) {
    case 0:  gemm_body<0, 0>(P0, s1c, s2c, hsT, partial, c, csh, 0, ldsF1, ldsB32); break;
    case 1:  gemm_body<1, 1>(P1, s1c, v2c, hsT, partial, c, csh, 0, ldsF1, ldsB32); break;
    case 2:  gemm_body<1, 1>(P1, s1c, v2c, hsT, partial, c, csh, 1, ldsF1, ldsB32); break;
    case 3:  gemm_body<2, 1>(P2, v1c, s2c, hsT, partial, c, csh, 0, ldsF1, ldsB32); break;
    case 4:  gemm_body<2, 1>(P2, v1c, s2c, hsT, partial, c, csh, 1, ldsF1, ldsB32); break;
    case 5:  gemm_body<3, 0>(P3, v1c, v2c, hsT, partial, c, csh, 0, ldsF1, ldsB32); break;
    case 6:  gemm_body<4, 1>(P4, v1c, v2c, hsT, partial, c, csh, 0, ldsF1, ldsB32); break;
    default: gemm_body<4, 1>(P4, v1c, v2c, hsT, partial, c, csh, 1, ldsF1, ldsB32); break;
  }
}

// ---------------- finalize: sum K-chunk partials, assemble output ----------------
__global__ __launch_bounds__(448) void k_fin(const float* __restrict__ partial, float* __restrict__ out, int nch)
{
  const int b = blockIdx.x, i = threadIdx.x;
  int w, rA, rB;
  if (i < 64)       { w = i; rA = b; rB = 896 + b; }
  else if (i < 256) { const int t = i - 64;  w = t / 3; const int j = t - 3 * w; rA = 128 + j * 128 + b; rB = 512 + j * 128 + b; }
  else              { const int t = i - 256; w = t / 3; const int k = t - 3 * w; rA = 1024 + k * 128 + b; rB = rA; }
  const float* pA = partial + (size_t)rA * 64 + w;
  const float* pB = partial + (size_t)rB * 64 + w;
  float sA = 0.f, sB = 0.f;
#pragma unroll 8
  for (int cc = 0; cc < nch; ++cc) {
    sA += pA[(size_t)cc * 90112];
    sB += pB[(size_t)cc * 90112];
  }
  const float A01 = 0.011048543f;            // 1/sqrt(2*64*64)
  const float sc = 0.015625f * 0.70710678f;  // ALPHA_2 * INV_SQ2
  float o;
  if (i < 64)       o = A01 * (sA + 0.57735027f * sB);  // t0 + INV_SQ3*t3
  else if (i < 256) o = A01 * (sA + sB);                // t1 + t2
  else              o = sc * sA;                        // eps-combined t4
  out[b * 448 + i] = o;
}

extern "C" void kernel_launch(void* const* d_in, const int* in_sizes, int n_in,
                              void* d_out, int out_size, void* d_ws, size_t ws_size,
                              hipStream_t stream)
{
  const float* emb = (const float*)d_in[0];
  const float* x1  = (const float*)d_in[1];
  const float* x2  = (const float*)d_in[2];
  const float* W0  = (const float*)d_in[3];
  const float* W1  = (const float*)d_in[4];
  const float* W2  = (const float*)d_in[5];
  const float* P0  = (const float*)d_in[6];
  const float* P1  = (const float*)d_in[7];
  const float* P2  = (const float*)d_in[8];
  const float* P3  = (const float*)d_in[9];
  const float* P4  = (const float*)d_in[10];
  float* out = (float*)d_out;
  char* ws = (char*)d_ws;

  // persistent region (live during tp_gemm): [0, 163840)
  float* hsT = (float*)ws;                                // 32768 B
  unsigned short* s1c = (unsigned short*)(ws + 32768);    // 16384 B
  unsigned short* v1c = (unsigned short*)(ws + 49152);    // 49152 B
  unsigned short* s2c = (unsigned short*)(ws + 98304);    // 16384 B
  unsigned short* v2c = (unsigned short*)(ws + 114688);   // 49152 B
  float* partial = (float*)(ws + 163840);                 // nch * 1408 * 64 * 4 B

  const int csh = (ws_size >= (size_t)163840 + ((size_t)360448 << 7)) ? 7 : 6;

  k_mlp<<<144, 256, 0, stream>>>(emb, W0, W1, W2, x1, x2, hsT, s1c, v1c, s2c, v2c);
  tp_gemm<<<8 << csh, 256, 0, stream>>>(P0, P1, P2, P3, P4, s1c, v1c, s2c, v2c, hsT, partial, csh);
  k_fin<<<128, 448, 0, stream>>>(partial, out, 1 << csh);
}

// Round 6
// 407.821 us; speedup vs baseline: 1.9110x; 1.0309x over previous
//
#include <hip/hip_runtime.h>

typedef float v4f __attribute__((ext_vector_type(4)));
typedef short v8s __attribute__((ext_vector_type(8)));

// round-to-nearest-even fp32 -> bf16
__device__ __forceinline__ unsigned short f2bf_rn(float f) {
  unsigned u = __float_as_uint(f);
  return (unsigned short)((u + 0x7fffu + ((u >> 16) & 1u)) >> 16);
}
__device__ __forceinline__ float bf2f(unsigned short h) {
  return __uint_as_float((unsigned)h << 16);
}

// tanh-approx gelu (JAX default) scaled by 1/PHI_C
__device__ __forceinline__ float gelu_phi(float x) {
  float t = tanhf(0.7978845608f * (x + 0.044715f * x * x * x));
  return 0.5f * x * (1.0f + t) * 1.5338375f;
}

// ---------------- fused 3-layer MLP (row-wise) + input prep ----------------
// blocks 0..127: MLP row b. blocks 128..135: x1 -> TRANSPOSED bf16 (s1T/v1T, u-major).
// blocks 136..143: x2 -> b-major bf16 (s2c/v2c) for register fragments.
__global__ __launch_bounds__(256) void k_mlp(const float* __restrict__ emb, const float* __restrict__ W0,
                                             const float* __restrict__ W1, const float* __restrict__ W2,
                                             const float* __restrict__ x1, const float* __restrict__ x2,
                                             float* __restrict__ hsT,
                                             unsigned short* __restrict__ s1T, unsigned short* __restrict__ v1T,
                                             unsigned short* __restrict__ s2c, unsigned short* __restrict__ v2c)
{
  const int blk = blockIdx.x, tid = threadIdx.x;
  if (blk < 128) {
    __shared__ float er[64];
    __shared__ float a1[256];
    __shared__ float a2[256];
    __shared__ float r3[4][64];
    const int b = blk;
    if (tid < 64) er[tid] = emb[b * 64 + tid];
    __syncthreads();
    {
      float s = 0.f;
#pragma unroll 8
      for (int x = 0; x < 64; ++x) s += er[x] * W0[x * 256 + tid];
      a1[tid] = gelu_phi(s * 0.125f);
    }
    __syncthreads();
    {
      float s = 0.f;
#pragma unroll 16
      for (int x = 0; x < 256; ++x) s += a1[x] * W1[x * 256 + tid];
      a2[tid] = gelu_phi(s * 0.0625f);
    }
    __syncthreads();
    {
      const int e = tid & 63, q = tid >> 6;
      float s = 0.f;
#pragma unroll 16
      for (int x = q * 64; x < q * 64 + 64; ++x) s += a2[x] * W2[x * 64 + e];
      r3[q][e] = s;
    }
    __syncthreads();
    if (tid < 64) {
      const float s = r3[0][tid] + r3[1][tid] + r3[2][tid] + r3[3][tid];
      hsT[tid * 128 + b] = gelu_phi(s * 0.0625f) * 0.125f;  // hs transposed [x][b]
    }
  } else if (blk < 136) {
    // x1 side, transposed (u-major) for per-step h reads
    for (int i = (blk - 128) * 256 + tid; i < 32768; i += 2048) {
      if (i < 8192) {
        const int u = i >> 7, b = i & 127;
        s1T[i] = f2bf_rn(x1[b * 256 + u]);  // s1T[u][b]
      } else {
        const int t = i - 8192, g = t >> 13, r = t & 8191;
        const int u = r >> 7, b = r & 127;
        v1T[t] = f2bf_rn(x1[b * 256 + 64 + u * 3 + g]);  // v1T[g][u][b]
      }
    }
  } else {
    // x2 side, b-major for register f2 fragments
    for (int i = (blk - 136) * 256 + tid; i < 32768; i += 2048) {
      if (i < 8192) {
        s2c[i] = f2bf_rn(x2[(i >> 6) * 256 + (i & 63)]);  // s2c[b][v]
      } else {
        const int t = i - 8192, g = t >> 13, r = t & 8191;
        v2c[t] = f2bf_rn(x2[(r >> 6) * 256 + 64 + (r & 63) * 3 + g]);  // v2c[g][b][v]
      }
    }
  }
}

// ---------------- fused tensor-product GEMM ----------------
// out-rows (M=1408) x K=(x,u,v)=262144 x N=w=64, A built in registers:
//   G0 (P0): rows b           : A = hs[x]*s1[u]*s2[v]            (full n)
//   G1 (P1): rows 128+j*128+b : A = hs[x]*s1[u]*v2_j[v]          (n-split)
//   G2 (P2): rows 512+i*128+b : A = hs[x]*v1_i[u]*s2[v]          (n-split)
//   G3 (P3): rows 896+b       : A = hs[x]*sum_i v1_i[u]*v2_i[v]  (full n)
//   G4 (P4): rows 1024+k*128+b: A = hs[x]*(v1_{k+1}[u]*v2_{k+2}[v]-v1_{k+2}[u]*v2_{k+1}[v]) (n-split)
// BK=128 per barrier epoch: 4 sub-tiles of 32k computed per single __syncthreads.
// h scalars from transposed global f1T (no f1 LDS). LDS = 2 buf x 4 sub B-tiles = 40KB.

template<int G, int HALF>
__device__ __forceinline__ void gemm_body(
    const float* __restrict__ P,
    const unsigned short* __restrict__ f1T,   // [comp][64 u][128 b] bf16
    const unsigned short* __restrict__ f2g,   // [comp][128 b][64 v] bf16
    const float* __restrict__ hsT,            // [64][128] f32
    float* __restrict__ partial,
    int c, int csh, int nh, unsigned* ldsB32)
{
  constexpr int NC   = (G == 0 || G == 3) ? 1 : 3;  // output comps per bh
  constexpr int NF2  = (G == 0 || G == 2) ? 1 : 3;  // f2 rows kept in regs
  constexpr int NH   = (G == 0 || G == 1) ? 1 : 3;  // f1 comps (h scalars)
  constexpr int RB   = (G == 0) ? 0 : (G == 1) ? 128 : (G == 2) ? 512 : (G == 3) ? 896 : 1024;
  constexpr int NF   = HALF ? 2 : 4;                // 16-wide n-tiles
  constexpr int ROWS = NF * 16;
  constexpr int NPF  = HALF ? 2 : 4;                // prefetch pairs per step

  const int tid = threadIdx.x;
  const int lane = tid & 63, w = tid >> 6, l16 = lane & 15, quad = lane >> 4;
  const int n0 = nh * 32;

  // staging mapping: FULL: 256 thr per 32kx64n sub; HALF: 128 thr per 32kx32n sub (2 subs/thr)
  const int tq = HALF ? (tid & 7) : (tid & 15);
  const int kp = HALF ? ((tid >> 3) & 15) : (tid >> 4);
  const int sg = HALF ? (tid >> 7) : 0;  // first staged sub (runtime, used in addresses only)

  const int nsteps = 1 << (11 - csh);
  const int kb = c << (18 - csh);
  const int x = kb >> 12;        // chunk is 2048- or 4096-aligned: x constant
  const int ub0 = (kb >> 6) & 63;

  int bidx[2];
  bidx[0] = w * 32 + l16;
  bidx[1] = w * 32 + 16 + l16;

  float hsx[2];
  hsx[0] = hsT[x * 128 + bidx[0]];
  hsx[1] = hsT[x * 128 + bidx[1]];

  // f2 fragments: [bh][comp][v-half], 8 bf16 each at v = hh*32 + quad*8 + j (once per block)
  v8s fr2[2][NF2][2];
#pragma unroll
  for (int bh = 0; bh < 2; ++bh)
#pragma unroll
    for (int m = 0; m < NF2; ++m)
#pragma unroll
      for (int hh = 0; hh < 2; ++hh)
        fr2[bh][m][hh] = *(const v8s*)(f2g + m * 8192 + bidx[bh] * 64 + hh * 32 + quad * 8);

  v4f acc[2][NC][NF];
#pragma unroll
  for (int bh = 0; bh < 2; ++bh)
#pragma unroll
    for (int cc = 0; cc < NC; ++cc)
#pragma unroll
      for (int nf = 0; nf < NF; ++nf) acc[bh][cc][nf] = (v4f){0.f, 0.f, 0.f, 0.f};

  const int swz_w = (tq & 3) << 2;          // write swizzle on k-pair dword idx
  const int swz_r = ((l16 >> 2) & 3) << 2;  // matching read swizzle

  float4 pa0[NPF], pa1[NPF];

  // global load of (step st, prefetch slot p); p literal at all call sites
  auto gload = [&](int st, int p) {
    const int sub = HALF ? (sg + 2 * p) : p;
    const int k0 = kb + st * 128 + sub * 32 + 2 * kp;
    const float* s = P + (size_t)k0 * 64 + n0 + 4 * tq;
    pa0[p] = *(const float4*)s;
    pa1[p] = *(const float4*)(s + 64);
  };
  auto bwrite = [&](int buf, int p) {
    const int sub = HALF ? (sg + 2 * p) : p;
    unsigned* dst = ldsB32 + ((buf * 4 + sub) * ROWS + 4 * tq) * 20 + (kp ^ swz_w);
    dst[0]  = (unsigned)f2bf_rn(pa0[p].x) | ((unsigned)f2bf_rn(pa1[p].x) << 16);
    dst[20] = (unsigned)f2bf_rn(pa0[p].y) | ((unsigned)f2bf_rn(pa1[p].y) << 16);
    dst[40] = (unsigned)f2bf_rn(pa0[p].z) | ((unsigned)f2bf_rn(pa1[p].z) << 16);
    dst[60] = (unsigned)f2bf_rn(pa0[p].w) | ((unsigned)f2bf_rn(pa1[p].w) << 16);
  };

  // prologue: stage step 0, prefetch step 1
#pragma unroll
  for (int p = 0; p < NPF; ++p) gload(0, p);
#pragma unroll
  for (int p = 0; p < NPF; ++p) bwrite(0, p);
#pragma unroll
  for (int p = 0; p < NPF; ++p) gload(1, p);
  __syncthreads();

  for (int st = 0; st < nsteps; ++st) {
    const int buf = st & 1;
    // hoist h scalars for both u-values of this step (coalesced 2B global loads, L2-hot)
    float hh[2][2][NH];  // [upair][bh][m]
#pragma unroll
    for (int up = 0; up < 2; ++up) {
      const int uu = (ub0 + st * 2 + up) & 63;
#pragma unroll
      for (int bh = 0; bh < 2; ++bh)
#pragma unroll
        for (int m = 0; m < NH; ++m)
          hh[up][bh][m] = hsx[bh] * bf2f(f1T[m * 8192 + uu * 128 + bidx[bh]]);
    }
    // compute 4 sub-tiles (one barrier epoch)
#pragma unroll
    for (int s = 0; s < 4; ++s) {
      const int up = s >> 1, vh = s & 1;
      v8s bfr[NF];
#pragma unroll
      for (int nf = 0; nf < NF; ++nf)
        bfr[nf] = *(const v8s*)&ldsB32[((buf * 4 + s) * ROWS + nf * 16 + l16) * 20 +
                                       ((quad * 4) ^ swz_r)];
#pragma unroll
      for (int bh = 0; bh < 2; ++bh) {
#pragma unroll
        for (int cc = 0; cc < NC; ++cc) {
          v8s af;
#pragma unroll
          for (int j = 0; j < 8; ++j) {
            float p;
            if constexpr (G == 0)
              p = hh[up][bh][0] * bf2f((unsigned short)fr2[bh][0][vh][j]);
            else if constexpr (G == 1)
              p = hh[up][bh][0] * bf2f((unsigned short)fr2[bh][cc][vh][j]);
            else if constexpr (G == 2)
              p = hh[up][bh][cc] * bf2f((unsigned short)fr2[bh][0][vh][j]);
            else if constexpr (G == 3)
              p = hh[up][bh][0] * bf2f((unsigned short)fr2[bh][0][vh][j])
                + hh[up][bh][1] * bf2f((unsigned short)fr2[bh][1][vh][j])
                + hh[up][bh][2] * bf2f((unsigned short)fr2[bh][2][vh][j]);
            else {
              const int i1 = (cc + 1) % 3, j2 = (cc + 2) % 3;
              p = hh[up][bh][i1] * bf2f((unsigned short)fr2[bh][j2][vh][j])
                - hh[up][bh][j2] * bf2f((unsigned short)fr2[bh][i1][vh][j]);
            }
            af[j] = (short)(__float_as_uint(p) >> 16);  // truncating bf16 (unbiased noise)
          }
#pragma unroll
          for (int nf = 0; nf < NF; ++nf)
            acc[bh][cc][nf] = __builtin_amdgcn_mfma_f32_16x16x32_bf16(af, bfr[nf], acc[bh][cc][nf], 0, 0, 0);
        }
      }
    }
    // stage next step (pa loaded during previous step: vmcnt long satisfied), refill pa
    if (st < nsteps - 1) {
#pragma unroll
      for (int p = 0; p < NPF; ++p) bwrite(buf ^ 1, p);
    }
    if (st < nsteps - 2) {
#pragma unroll
      for (int p = 0; p < NPF; ++p) gload(st + 2, p);
    }
    __syncthreads();  // one barrier per 128 k
  }

  // epilogue: C/D layout col=l16, row=quad*4+r ; disjoint per-chunk/half partials
#pragma unroll
  for (int bh = 0; bh < 2; ++bh)
#pragma unroll
    for (int cc = 0; cc < NC; ++cc)
#pragma unroll
      for (int nf = 0; nf < NF; ++nf)
#pragma unroll
        for (int r = 0; r < 4; ++r) {
          const int row = RB + cc * 128 + w * 32 + bh * 16 + quad * 4 + r;
          const int col = n0 + nf * 16 + l16;
          partial[((size_t)c * 1408 + row) * 64 + col] = acc[bh][cc][nf][r];
        }
}

// block slots per chunk (cost-interleaved): [G0, G1h0, G1h1, G2h0, G2h1, G3, G4h0, G4h1]
__global__ __launch_bounds__(256, 2) void tp_gemm(
    const float* __restrict__ P0, const float* __restrict__ P1, const float* __restrict__ P2,
    const float* __restrict__ P3, const float* __restrict__ P4,
    const unsigned short* __restrict__ s1T, const unsigned short* __restrict__ v1T,
    const unsigned short* __restrict__ s2c, const unsigned short* __restrict__ v2c,
    const float* __restrict__ hsT, float* __restrict__ partial, int csh)
{
  __shared__ __align__(16) unsigned ldsB32[10240];  // 2 buf x 4 sub x 64 n x 20 dw = 40 KB
  const int slot = blockIdx.x & 7;
  const int c = blockIdx.x >> 3;
  switch (slot) {
    case 0:  gemm_body<0, 0>(P0, s1T, s2c, hsT, partial, c, csh, 0, ldsB32); break;
    case 1:  gemm_body<1, 1>(P1, s1T, v2c, hsT, partial, c, csh, 0, ldsB32); break;
    case 2:  gemm_body<1, 1>(P1, s1T, v2c, hsT, partial, c, csh, 1, ldsB32); break;
    case 3:  gemm_body<2, 1>(P2, v1T, s2c, hsT, partial, c, csh, 0, ldsB32); break;
    case 4:  gemm_body<2, 1>(P2, v1T, s2c, hsT, partial, c, csh, 1, ldsB32); break;
    case 5:  gemm_body<3, 0>(P3, v1T, v2c, hsT, partial, c, csh, 0, ldsB32); break;
    case 6:  gemm_body<4, 1>(P4, v1T, v2c, hsT, partial, c, csh, 0, ldsB32); break;
    default: gemm_body<4, 1>(P4, v1T, v2c, hsT, partial, c, csh, 1, ldsB32); break;
  }
}

// ---------------- finalize: coalesced chunk-sum + output assembly ----------------
// One block per b. Slot s = r*64+w, r in 0..10; rowOf(r) = r*128 + b for ALL row classes.
// Wave lanes span w (contiguous 256B per chunk) -> fully coalesced.
__global__ __launch_bounds__(512) void k_fin(const float* __restrict__ partial, float* __restrict__ out, int nch)
{
  __shared__ float sums[704];
  const int b = blockIdx.x, tid = threadIdx.x;
  const int r0 = tid >> 6, w0 = tid & 63;
  const int row0 = r0 * 128 + b;
  const int r1 = (tid + 512) >> 6;     // 8..10 for tid<192
  const int row1 = r1 * 128 + b;
  float a0 = 0.f, a1 = 0.f;
  const float* p0 = partial + (size_t)row0 * 64 + w0;
  const float* p1 = partial + (size_t)row1 * 64 + w0;
#pragma unroll 4
  for (int c = 0; c < nch; ++c) {
    const size_t off = (size_t)c * 90112;
    a0 += p0[off];
    if (tid < 192) a1 += p1[off];
  }
  sums[tid] = a0;
  if (tid < 192) sums[512 + tid] = a1;
  __syncthreads();
  if (tid < 448) {
    const float A01 = 0.011048543f;            // 1/sqrt(2*64*64)
    const float sc = 0.015625f * 0.70710678f;  // ALPHA_2 * INV_SQ2
    float o;
    if (tid < 64) {
      o = A01 * (sums[tid] + 0.57735027f * sums[7 * 64 + tid]);  // t0 + INV_SQ3*t3
    } else if (tid < 256) {
      const int t = tid - 64, ww = t / 3, j = t - 3 * ww;
      o = A01 * (sums[(1 + j) * 64 + ww] + sums[(4 + j) * 64 + ww]);  // t1 + t2
    } else {
      const int t = tid - 256, ww = t / 3, k = t - 3 * ww;
      o = sc * sums[(8 + k) * 64 + ww];  // eps-combined t4
    }
    out[b * 448 + tid] = o;
  }
}

extern "C" void kernel_launch(void* const* d_in, const int* in_sizes, int n_in,
                              void* d_out, int out_size, void* d_ws, size_t ws_size,
                              hipStream_t stream)
{
  const float* emb = (const float*)d_in[0];
  const float* x1  = (const float*)d_in[1];
  const float* x2  = (const float*)d_in[2];
  const float* W0  = (const float*)d_in[3];
  const float* W1  = (const float*)d_in[4];
  const float* W2  = (const float*)d_in[5];
  const float* P0  = (const float*)d_in[6];
  const float* P1  = (const float*)d_in[7];
  const float* P2  = (const float*)d_in[8];
  const float* P3  = (const float*)d_in[9];
  const float* P4  = (const float*)d_in[10];
  float* out = (float*)d_out;
  char* ws = (char*)d_ws;

  // persistent region (live during tp_gemm): [0, 163840)
  float* hsT = (float*)ws;                                // 32768 B
  unsigned short* s1T = (unsigned short*)(ws + 32768);    // 16384 B  [u][b]
  unsigned short* v1T = (unsigned short*)(ws + 49152);    // 49152 B  [g][u][b]
  unsigned short* s2c = (unsigned short*)(ws + 98304);    // 16384 B  [b][v]
  unsigned short* v2c = (unsigned short*)(ws + 114688);   // 49152 B  [g][b][v]
  float* partial = (float*)(ws + 163840);                 // nch * 1408 * 64 * 4 B

  const int csh = (ws_size >= (size_t)163840 + ((size_t)360448 << 7)) ? 7 : 6;

  k_mlp<<<144, 256, 0, stream>>>(emb, W0, W1, W2, x1, x2, hsT, s1T, v1T, s2c, v2c);
  tp_gemm<<<8 << csh, 256, 0, stream>>>(P0, P1, P2, P3, P4, s1T, v1T, s2c, v2c, hsT, partial, csh);
  k_fin<<<128, 512, 0, stream>>>(partial, out, 1 << csh);
}